// Round 6
// baseline (414.697 us; speedup 1.0000x reference)
//
#include <hip/hip_runtime.h>

typedef __attribute__((ext_vector_type(4))) float f32x4;
typedef __attribute__((ext_vector_type(8))) short s16x8;  // 8 x bf16 fragment

#define DEVI static __device__ __forceinline__

constexpr int BB = 4, HH = 8, TT = 2048, DD = 256;

// fp32 -> bf16 round-to-nearest-even
DEVI short f2bf(float f) {
  union { float f; unsigned u; } x; x.f = f;
  unsigned r = x.u + 0x7fffu + ((x.u >> 16) & 1u);
  return (short)(r >> 16);
}

// async global->LDS, 16B per lane; LDS dest = wave-uniform base + lane*16
DEVI void gl16(const short* g, short* l) {
  __builtin_amdgcn_global_load_lds(
      (const __attribute__((address_space(1))) void*)g,
      (__attribute__((address_space(3))) void*)l, 16, 0, 0);
}

// ---------------------------------------------------------------------------
// Kernel 1a: vectorized cast r' -> rbf, E -> Ebf
// ---------------------------------------------------------------------------
__global__ void cast_rE(const float* __restrict__ r, const float* __restrict__ E,
                        short* __restrict__ rbf, short* __restrict__ Ebf) {
  int idx = blockIdx.x * blockDim.x + threadIdx.x;
  int stride = gridDim.x * blockDim.x;
  int nR = BB * TT * DD / 8, nE = HH * DD * DD / 8;
  for (int i = idx; i < nR; i += stride) {
    f32x4 x0 = ((const f32x4*)r)[2 * i], x1 = ((const f32x4*)r)[2 * i + 1];
    s16x8 o;
    #pragma unroll
    for (int e = 0; e < 4; ++e) { o[e] = f2bf(x0[e]); o[4 + e] = f2bf(x1[e]); }
    ((s16x8*)rbf)[i] = o;
  }
  for (int i = idx; i < nE; i += stride) {
    f32x4 x0 = ((const f32x4*)E)[2 * i], x1 = ((const f32x4*)E)[2 * i + 1];
    s16x8 o;
    #pragma unroll
    for (int e = 0; e < 4; ++e) { o[e] = f2bf(x0[e]); o[4 + e] = f2bf(x1[e]); }
    ((s16x8*)Ebf)[i] = o;
  }
}

// ---------------------------------------------------------------------------
// Kernel 1b: Qt[h][j][i] = bf16(Q[h][i][j]) via 64x64 LDS transpose tiles
// ---------------------------------------------------------------------------
__global__ void qt_prep(const float* __restrict__ Q, short* __restrict__ Qt) {
  __shared__ float t[64][65];
  int tid = threadIdx.x;
  int h = blockIdx.y, bx = blockIdx.x;
  int i0 = (bx >> 2) * 64, j0 = (bx & 3) * 64;
  const float* Qh = Q + (size_t)h * DD * DD;
  int rr = tid >> 2, cq = tid & 3;
  #pragma unroll
  for (int it = 0; it < 4; ++it) {
    int col = cq * 16 + it * 4;
    f32x4 v = *(const f32x4*)(Qh + (size_t)(i0 + rr) * DD + j0 + col);
    #pragma unroll
    for (int e = 0; e < 4; ++e) t[rr][col + e] = v[e];
  }
  __syncthreads();
  int j = tid >> 2, iq = tid & 3;
  short* dst = Qt + (size_t)h * DD * DD + (size_t)(j0 + j) * DD + i0;
  #pragma unroll
  for (int it = 0; it < 4; ++it) {
    int ic = iq * 16 + it * 4;
    short o[4];
    #pragma unroll
    for (int e = 0; e < 4; ++e) o[e] = f2bf(t[ic + e][j]);
    *(int2*)(dst + ic) = *(int2*)o;
  }
}

// ---------------------------------------------------------------------------
// Kernel 2: merged prep GEMM. mode = bx>>7:
// mode 0: Abf[b][h][t][j] = rbf[b] @ Qt[h]^T   (M=2048, N=256)
// mode 1: Vt[b][h][i][u]  = Ebf[h] @ rbf[b]^T  (M=256, N=2048)
// ---------------------------------------------------------------------------
__global__ __launch_bounds__(256, 2)
void prep_gemm(const short* __restrict__ rbf, const short* __restrict__ Qt,
               const short* __restrict__ Ebf, short* __restrict__ Abf,
               short* __restrict__ Vtbf) {
  __shared__ __align__(16) short w_lds[64 * 256];
  int tid = threadIdx.x, lane = tid & 63, wid = tid >> 6;
  int h = blockIdx.y, b = blockIdx.z;
  int mode = blockIdx.x >> 7, bx = blockIdx.x & 127;
  const short* X; const short* W; short* C; int ldC, m0, n0;
  if (mode == 0) {
    m0 = (bx >> 2) * 64; n0 = (bx & 3) * 64;
    X = rbf + (size_t)b * TT * DD;
    W = Qt + (size_t)h * DD * DD;
    C = Abf + (size_t)(b * HH + h) * TT * DD; ldC = DD;
  } else {
    m0 = (bx & 3) * 64; n0 = (bx >> 2) * 64;
    X = Ebf + (size_t)h * DD * DD;
    W = rbf + (size_t)b * TT * DD;
    C = Vtbf + (size_t)(b * HH + h) * DD * TT; ldC = TT;
  }
  #pragma unroll
  for (int it = 0; it < 8; ++it) {
    int t = it * 256 + tid;
    int row = t >> 5, kb = t & 31;
    s16x8 v = *(const s16x8*)(W + (size_t)(n0 + row) * DD + kb * 8);
    *(s16x8*)(&w_lds[row * 256 + ((kb ^ (row & 7)) << 3)]) = v;
  }
  s16x8 a[8];
  {
    const short* xrow = X + (size_t)(m0 + wid * 16 + (lane & 15)) * DD + (lane >> 4) * 8;
    #pragma unroll
    for (int ks = 0; ks < 8; ++ks) a[ks] = *(const s16x8*)(xrow + ks * 32);
  }
  __syncthreads();
  f32x4 c[4] = {};
  #pragma unroll
  for (int n = 0; n < 4; ++n) {
    int row = n * 16 + (lane & 15);
    #pragma unroll
    for (int ks = 0; ks < 8; ++ks) {
      int kb = ks * 4 + (lane >> 4);
      s16x8 bfr = *(const s16x8*)(&w_lds[row * 256 + ((kb ^ (row & 7)) << 3)]);
      c[n] = __builtin_amdgcn_mfma_f32_16x16x32_bf16(a[ks], bfr, c[n], 0, 0, 0);
    }
  }
  __syncthreads();
  #pragma unroll
  for (int n = 0; n < 4; ++n) {
    int col = n * 16 + (lane & 15);
    int cb = col >> 3;
    #pragma unroll
    for (int rr = 0; rr < 4; ++rr) {
      int row = wid * 16 + (lane >> 4) * 4 + rr;
      w_lds[row * 64 + ((cb ^ (row & 7)) << 3) + (col & 7)] = f2bf(c[n][rr]);
    }
  }
  __syncthreads();
  #pragma unroll
  for (int q = 0; q < 2; ++q) {
    int t = q * 256 + tid;
    int row = t >> 3, cb = t & 7;
    s16x8 v = *(const s16x8*)(&w_lds[row * 64 + ((cb ^ (row & 7)) << 3)]);
    *(s16x8*)(&C[(size_t)(m0 + row) * ldC + n0 + cb * 8]) = v;
  }
}

// ---------------------------------------------------------------------------
// Kernel 3: causal main loop. 512 blocks, one 128-row t-tile each:
//   z = q&15; tt = (q<256) ? z : 15-z; hb = (q>>4)&15 | (q>=256 ? 16 : 0)
// All blocks sweep u = 0..(2tt+2) ascending (temporal L2/L3 alignment).
// CU pair (q, q+256) has complementary tiles -> 17 units/CU balanced.
// Alternating single-buffer pipeline: STAGE_V hidden under S-phase,
// STAGE_K(next) hidden under PV-phase. LDS 80KB -> 2 blocks/CU.
// ---------------------------------------------------------------------------
__global__ __launch_bounds__(256, 2)
void attn_main(const short* __restrict__ Abf, const short* __restrict__ Kbf,
               const short* __restrict__ Vtb, float* __restrict__ out) {
  __shared__ __align__(16) short k_lds[64 * 256];   // 32KB [u_loc][j swz]
  __shared__ __align__(16) short v_lds[256 * 64];   // 32KB [i][u_loc swz]
  __shared__ __align__(16) short s_lds[128 * 64];   // 16KB [t_loc][u_loc swz]
  int tid = threadIdx.x, lane = tid & 63, wid = tid >> 6;
  int q = blockIdx.x;
  int g = q >> 8, rem = q & 255;
  int z = rem & 15;
  int tt = g ? (15 - z) : z;
  int hb = (rem >> 4) | (g << 4);
  int h = hb & 7, b = hb >> 3;

  const short* Ab0 = Abf + (size_t)(b * HH + h) * TT * DD;
  const short* Kb = Kbf + (size_t)b * TT * DD;
  const short* Vb = Vtb + (size_t)(b * HH + h) * DD * TT;

#define STAGE_K(iu_) do {                                                     \
    int U_ = (iu_) * 64;                                                      \
    _Pragma("unroll")                                                         \
    for (int c_ = 0; c_ < 8; ++c_) {                                          \
      int kc_ = wid * 8 + c_;                                                 \
      int row_ = kc_ * 2 + (lane >> 5);                                       \
      int blk_ = lane & 31;                                                   \
      gl16(Kb + (size_t)(U_ + row_) * DD + ((blk_ ^ (row_ & 7)) << 3),        \
           &k_lds[kc_ * 512]);                                                \
    }                                                                         \
  } while (0)

#define STAGE_V(iu_) do {                                                     \
    int U_ = (iu_) * 64;                                                      \
    _Pragma("unroll")                                                         \
    for (int c_ = 0; c_ < 8; ++c_) {                                          \
      int vc_ = wid * 8 + c_;                                                 \
      int row_ = vc_ * 8 + (lane >> 3);                                       \
      int cb_ = lane & 7;                                                     \
      gl16(Vb + (size_t)row_ * TT + U_ + ((cb_ ^ (row_ & 7)) << 3),           \
           &v_lds[vc_ * 512]);                                                \
    }                                                                         \
  } while (0)

  // A fragments: 2 row-blocks x 8 k-steps, held for the whole t-tile
  s16x8 a[2][8];
  {
    const short* abase = Ab0 + (size_t)(tt * 128 + wid * 32 + (lane & 15)) * DD + ((lane >> 4) << 3);
    #pragma unroll
    for (int rb = 0; rb < 2; ++rb)
      #pragma unroll
      for (int ks = 0; ks < 8; ++ks)
        a[rb][ks] = *(const s16x8*)(abase + rb * 16 * DD + ks * 32);
  }
  f32x4 acc[2][16] = {};
  int nU = 2 * tt + 2;

  STAGE_K(0);
  asm volatile("s_waitcnt vmcnt(0)" ::: "memory");
  __builtin_amdgcn_s_barrier();

  #pragma unroll 1
  for (int iu = 0; iu < nU; ++iu) {
    int U = iu * 64;
    STAGE_V(iu);                      // V(iu) latency hidden under S-phase

    // ---- S phase: S = A @ K^T (64 u cols), masked, packed to s_lds ----
    #pragma unroll
    for (int hh = 0; hh < 2; ++hh) {
      f32x4 s[2][2] = {{{0,0,0,0},{0,0,0,0}},{{0,0,0,0},{0,0,0,0}}};
      #pragma unroll
      for (int n2 = 0; n2 < 2; ++n2) {
        int row = (hh * 2 + n2) * 16 + (lane & 15);
        #pragma unroll
        for (int ks = 0; ks < 8; ++ks) {
          int kb = ks * 4 + (lane >> 4);
          s16x8 bfr = *(const s16x8*)(&k_lds[row * 256 + ((kb ^ (row & 7)) << 3)]);
          s[0][n2] = __builtin_amdgcn_mfma_f32_16x16x32_bf16(a[0][ks], bfr, s[0][n2], 0, 0, 0);
          s[1][n2] = __builtin_amdgcn_mfma_f32_16x16x32_bf16(a[1][ks], bfr, s[1][n2], 0, 0, 0);
        }
      }
      #pragma unroll
      for (int rb = 0; rb < 2; ++rb) {
        #pragma unroll
        for (int n2 = 0; n2 < 2; ++n2) {
          #pragma unroll
          for (int rr = 0; rr < 4; ++rr) {
            int t_loc = wid * 32 + rb * 16 + (lane >> 4) * 4 + rr;
            int kloc = hh * 32 + n2 * 16 + (lane & 15);
            int u_glob = U + kloc;
            float v = (u_glob <= tt * 128 + t_loc) ? s[rb][n2][rr] : 0.0f;
            int cb = kloc >> 3;
            s_lds[t_loc * 64 + ((cb ^ (t_loc & 7)) << 3) + (kloc & 7)] = f2bf(v);
          }
        }
      }
    }
    asm volatile("s_waitcnt lgkmcnt(0)" ::: "memory");
    asm volatile("s_waitcnt vmcnt(0)" ::: "memory");   // V(iu) landed
    __builtin_amdgcn_s_barrier();

    if (iu + 1 < nU) STAGE_K(iu + 1); // K(iu+1) latency hidden under PV

    // ---- PV phase: acc += S @ V (k=64) ----
    #pragma unroll
    for (int ks2 = 0; ks2 < 2; ++ks2) {
      int kb = ks2 * 4 + (lane >> 4);
      s16x8 af[2];
      #pragma unroll
      for (int rb = 0; rb < 2; ++rb) {
        int R = wid * 32 + rb * 16 + (lane & 15);
        af[rb] = *(const s16x8*)(&s_lds[R * 64 + ((kb ^ (R & 7)) << 3)]);
      }
      #pragma unroll
      for (int ni = 0; ni < 16; ++ni) {
        int vrow = ni * 16 + (lane & 15);
        s16x8 bv = *(const s16x8*)(&v_lds[vrow * 64 + ((kb ^ (vrow & 7)) << 3)]);
        acc[0][ni] = __builtin_amdgcn_mfma_f32_16x16x32_bf16(af[0], bv, acc[0][ni], 0, 0, 0);
        acc[1][ni] = __builtin_amdgcn_mfma_f32_16x16x32_bf16(af[1], bv, acc[1][ni], 0, 0, 0);
      }
    }
    asm volatile("s_waitcnt lgkmcnt(0)" ::: "memory");
    asm volatile("s_waitcnt vmcnt(0)" ::: "memory");   // K(iu+1) landed
    __builtin_amdgcn_s_barrier();
  }

  // epilogue: head partial sum via atomics
  float* ob = out + ((size_t)b * TT + tt * 128 + wid * 32) * DD;
  #pragma unroll
  for (int rb = 0; rb < 2; ++rb) {
    #pragma unroll
    for (int ni = 0; ni < 16; ++ni) {
      int col = ni * 16 + (lane & 15);
      #pragma unroll
      for (int rr = 0; rr < 4; ++rr) {
        int row = rb * 16 + (lane >> 4) * 4 + rr;
        atomicAdd(&ob[row * DD + col], acc[rb][ni][rr]);
      }
    }
  }
#undef STAGE_K
#undef STAGE_V
}

// ---------------------------------------------------------------------------
extern "C" void kernel_launch(void* const* d_in, const int* in_sizes, int n_in,
                              void* d_out, int out_size, void* d_ws, size_t ws_size,
                              hipStream_t stream) {
  const float* r = (const float*)d_in[0];
  const float* Q = (const float*)d_in[1];
  const float* E = (const float*)d_in[2];
  float* out = (float*)d_out;
  char* ws = (char*)d_ws;

  size_t off = 0;
  short* rbf = (short*)(ws + off); off += (size_t)BB * TT * DD * 2;      // 4 MiB
  short* Qt  = (short*)(ws + off); off += (size_t)HH * DD * DD * 2;      // 1 MiB
  short* Ebf = (short*)(ws + off); off += (size_t)HH * DD * DD * 2;      // 1 MiB
  short* Abf = (short*)(ws + off); off += (size_t)BB * HH * TT * DD * 2; // 32 MiB
  short* Vtb = (short*)(ws + off); off += (size_t)BB * HH * DD * TT * 2; // 32 MiB

  hipMemsetAsync(d_out, 0, (size_t)out_size * sizeof(float), stream);
  cast_rE<<<1024, 256, 0, stream>>>(r, E, rbf, Ebf);
  qt_prep<<<dim3(16, HH), 256, 0, stream>>>(Q, Qt);
  prep_gemm<<<dim3(256, HH, BB), 256, 0, stream>>>(rbf, Qt, Ebf, Abf, Vtb);
  attn_main<<<dim3(512, 1, 1), 256, 0, stream>>>(Abf, rbf, Vtb, out);
}

// Round 7
// 235.042 us; speedup vs baseline: 1.7643x; 1.7643x over previous
//
#include <hip/hip_runtime.h>

typedef __attribute__((ext_vector_type(4))) float f32x4;
typedef __attribute__((ext_vector_type(8))) short s16x8;  // 8 x bf16 fragment

#define DEVI static __device__ __forceinline__

constexpr int BB = 4, HH = 8, TT = 2048, DD = 256;

// fp32 -> bf16 round-to-nearest-even
DEVI short f2bf(float f) {
  union { float f; unsigned u; } x; x.f = f;
  unsigned r = x.u + 0x7fffu + ((x.u >> 16) & 1u);
  return (short)(r >> 16);
}

// async global->LDS, 16B per lane; LDS dest = wave-uniform base + lane*16
DEVI void gl16(const short* g, short* l) {
  __builtin_amdgcn_global_load_lds(
      (const __attribute__((address_space(1))) void*)g,
      (__attribute__((address_space(3))) void*)l, 16, 0, 0);
}

// job table: 24 jobs per (h,b), descending work for greedy LPT balance.
// tt>=8 split into two u-halves; tt<8 whole sweep. units are 32-row u-tiles.
__device__ const signed char g_jtt[24] = {15,15, 7,14,14,13,13, 6,12,12,11,11, 5,10,10, 9, 9, 4, 8, 8, 3, 2, 1, 0};
__device__ const signed char g_jlo[24] = { 0,32, 0, 0,30, 0,28, 0, 0,26, 0,24, 0, 0,22, 0,20, 0, 0,18, 0, 0, 0, 0};
__device__ const signed char g_jn [24] = {32,32,32,30,30,28,28,28,26,26,24,24,24,22,22,20,20,20,18,18,16,12, 8, 4};

// ---------------------------------------------------------------------------
// Kernel 1a: vectorized cast r' -> rbf, E -> Ebf
// ---------------------------------------------------------------------------
__global__ void cast_rE(const float* __restrict__ r, const float* __restrict__ E,
                        short* __restrict__ rbf, short* __restrict__ Ebf) {
  int idx = blockIdx.x * blockDim.x + threadIdx.x;
  int stride = gridDim.x * blockDim.x;
  int nR = BB * TT * DD / 8, nE = HH * DD * DD / 8;
  for (int i = idx; i < nR; i += stride) {
    f32x4 x0 = ((const f32x4*)r)[2 * i], x1 = ((const f32x4*)r)[2 * i + 1];
    s16x8 o;
    #pragma unroll
    for (int e = 0; e < 4; ++e) { o[e] = f2bf(x0[e]); o[4 + e] = f2bf(x1[e]); }
    ((s16x8*)rbf)[i] = o;
  }
  for (int i = idx; i < nE; i += stride) {
    f32x4 x0 = ((const f32x4*)E)[2 * i], x1 = ((const f32x4*)E)[2 * i + 1];
    s16x8 o;
    #pragma unroll
    for (int e = 0; e < 4; ++e) { o[e] = f2bf(x0[e]); o[4 + e] = f2bf(x1[e]); }
    ((s16x8*)Ebf)[i] = o;
  }
}

// ---------------------------------------------------------------------------
// Kernel 1b: Qt[h][j][i] = bf16(Q[h][i][j]) via 64x64 LDS transpose tiles
// ---------------------------------------------------------------------------
__global__ void qt_prep(const float* __restrict__ Q, short* __restrict__ Qt) {
  __shared__ float t[64][65];
  int tid = threadIdx.x;
  int h = blockIdx.y, bx = blockIdx.x;
  int i0 = (bx >> 2) * 64, j0 = (bx & 3) * 64;
  const float* Qh = Q + (size_t)h * DD * DD;
  int rr = tid >> 2, cq = tid & 3;
  #pragma unroll
  for (int it = 0; it < 4; ++it) {
    int col = cq * 16 + it * 4;
    f32x4 v = *(const f32x4*)(Qh + (size_t)(i0 + rr) * DD + j0 + col);
    #pragma unroll
    for (int e = 0; e < 4; ++e) t[rr][col + e] = v[e];
  }
  __syncthreads();
  int j = tid >> 2, iq = tid & 3;
  short* dst = Qt + (size_t)h * DD * DD + (size_t)(j0 + j) * DD + i0;
  #pragma unroll
  for (int it = 0; it < 4; ++it) {
    int ic = iq * 16 + it * 4;
    short o[4];
    #pragma unroll
    for (int e = 0; e < 4; ++e) o[e] = f2bf(t[ic + e][j]);
    *(int2*)(dst + ic) = *(int2*)o;
  }
}

// ---------------------------------------------------------------------------
// Kernel 2: merged prep GEMM. mode = bx>>7:
// mode 0: Abf[b][h][t][j] = rbf[b] @ Qt[h]^T   (M=2048, N=256)
// mode 1: Vt[b][h][i][u]  = Ebf[h] @ rbf[b]^T  (M=256, N=2048)
// ---------------------------------------------------------------------------
__global__ __launch_bounds__(256, 2)
void prep_gemm(const short* __restrict__ rbf, const short* __restrict__ Qt,
               const short* __restrict__ Ebf, short* __restrict__ Abf,
               short* __restrict__ Vtbf) {
  __shared__ __align__(16) short w_lds[64 * 256];
  int tid = threadIdx.x, lane = tid & 63, wid = tid >> 6;
  int h = blockIdx.y, b = blockIdx.z;
  int mode = blockIdx.x >> 7, bx = blockIdx.x & 127;
  const short* X; const short* W; short* C; int ldC, m0, n0;
  if (mode == 0) {
    m0 = (bx >> 2) * 64; n0 = (bx & 3) * 64;
    X = rbf + (size_t)b * TT * DD;
    W = Qt + (size_t)h * DD * DD;
    C = Abf + (size_t)(b * HH + h) * TT * DD; ldC = DD;
  } else {
    m0 = (bx & 3) * 64; n0 = (bx >> 2) * 64;
    X = Ebf + (size_t)h * DD * DD;
    W = rbf + (size_t)b * TT * DD;
    C = Vtbf + (size_t)(b * HH + h) * DD * TT; ldC = TT;
  }
  #pragma unroll
  for (int it = 0; it < 8; ++it) {
    int t = it * 256 + tid;
    int row = t >> 5, kb = t & 31;
    s16x8 v = *(const s16x8*)(W + (size_t)(n0 + row) * DD + kb * 8);
    *(s16x8*)(&w_lds[row * 256 + ((kb ^ (row & 7)) << 3)]) = v;
  }
  s16x8 a[8];
  {
    const short* xrow = X + (size_t)(m0 + wid * 16 + (lane & 15)) * DD + (lane >> 4) * 8;
    #pragma unroll
    for (int ks = 0; ks < 8; ++ks) a[ks] = *(const s16x8*)(xrow + ks * 32);
  }
  __syncthreads();
  f32x4 c[4] = {};
  #pragma unroll
  for (int n = 0; n < 4; ++n) {
    int row = n * 16 + (lane & 15);
    #pragma unroll
    for (int ks = 0; ks < 8; ++ks) {
      int kb = ks * 4 + (lane >> 4);
      s16x8 bfr = *(const s16x8*)(&w_lds[row * 256 + ((kb ^ (row & 7)) << 3)]);
      c[n] = __builtin_amdgcn_mfma_f32_16x16x32_bf16(a[ks], bfr, c[n], 0, 0, 0);
    }
  }
  __syncthreads();
  #pragma unroll
  for (int n = 0; n < 4; ++n) {
    int col = n * 16 + (lane & 15);
    int cb = col >> 3;
    #pragma unroll
    for (int rr = 0; rr < 4; ++rr) {
      int row = wid * 16 + (lane >> 4) * 4 + rr;
      w_lds[row * 64 + ((cb ^ (row & 7)) << 3) + (col & 7)] = f2bf(c[n][rr]);
    }
  }
  __syncthreads();
  #pragma unroll
  for (int q = 0; q < 2; ++q) {
    int t = q * 256 + tid;
    int row = t >> 3, cb = t & 7;
    s16x8 v = *(const s16x8*)(&w_lds[row * 64 + ((cb ^ (row & 7)) << 3)]);
    *(s16x8*)(&C[(size_t)(m0 + row) * ldC + n0 + cb * 8]) = v;
  }
}

// ---------------------------------------------------------------------------
// Kernel 3: causal main loop. 768 blocks: j = q>>5 indexes the 24-entry job
// table (tt, u_lo, u_n), descending work -> greedy LPT balance (768 jobs on
// 512 resident slots). hb = q&31, h = hb>>2, b = hb&3 so q mod 8 clusters
// same-b (K) and 4 V-slices per XCD. All full-range jobs sweep u from 0
// ascending -> L2/L3 temporal alignment. K,V dbuf via global_load_lds with
// counted vmcnt; 72KB LDS -> 2 blocks/CU, 2 waves/SIMD.
// ---------------------------------------------------------------------------
__global__ __launch_bounds__(256, 2)
void attn_main(const short* __restrict__ Abf, const short* __restrict__ Kbf,
               const short* __restrict__ Vtb, float* __restrict__ out) {
  __shared__ __align__(16) short k_lds[2][32 * 256];   // 2 x 16KB [u_loc][j swz]
  __shared__ __align__(16) short v_lds[2][256 * 32];   // 2 x 16KB [i][u_loc swz]
  __shared__ __align__(16) short s_lds[128 * 32];      // 8KB [t_loc][u_loc swz]
  int tid = threadIdx.x, lane = tid & 63, wid = tid >> 6;
  int q = blockIdx.x;
  int jj = q >> 5, hb = q & 31;
  int h = hb >> 2, b = hb & 3;
  int tt = g_jtt[jj];
  int u_lo = g_jlo[jj];
  int u_n = g_jn[jj];

  const short* Ab0 = Abf + (size_t)(b * HH + h) * TT * DD;
  const short* Kb = Kbf + (size_t)b * TT * DD;
  const short* Vb = Vtb + (size_t)(b * HH + h) * DD * TT;

#define STAGE(bufi, iu_) do {                                                  \
    int U_ = (iu_) * 32;                                                       \
    _Pragma("unroll")                                                          \
    for (int c_ = 0; c_ < 4; ++c_) {   /* K: 16 x 1KB chunks, 4/wave */        \
      int kc_ = wid * 4 + c_;                                                  \
      int row_ = kc_ * 2 + (lane >> 5);                                        \
      int blk_ = lane & 31;                                                    \
      gl16(Kb + (size_t)(U_ + row_) * DD + ((blk_ ^ (row_ & 7)) << 3),         \
           &k_lds[bufi][kc_ * 512]);                                           \
    }                                                                          \
    _Pragma("unroll")                                                          \
    for (int c_ = 0; c_ < 4; ++c_) {   /* V: 16 x 1KB chunks, 4/wave */        \
      int vc_ = wid * 4 + c_;                                                  \
      int row_ = vc_ * 16 + (lane >> 2);                                       \
      int blk_ = lane & 3;                                                     \
      gl16(Vb + (size_t)row_ * TT + U_ + (((blk_ ^ (row_ & 3))) << 3),         \
           &v_lds[bufi][vc_ * 512]);                                           \
    }                                                                          \
  } while (0)

  // A fragments: 2 row-blocks x 8 k-steps, held for the whole job
  s16x8 a[2][8];
  {
    const short* abase = Ab0 + (size_t)(tt * 128 + wid * 32 + (lane & 15)) * DD + ((lane >> 4) << 3);
    #pragma unroll
    for (int rb = 0; rb < 2; ++rb)
      #pragma unroll
      for (int ks = 0; ks < 8; ++ks)
        a[rb][ks] = *(const s16x8*)(abase + rb * 16 * DD + ks * 32);
  }
  f32x4 acc[2][16] = {};

  STAGE(0, u_lo);  // prologue: first tile -> buffer 0 (8 gl_lds per wave)

  #pragma unroll 1
  for (int s2 = 0; s2 < u_n; ++s2) {
    int cur = s2 & 1;
    if (s2 + 1 < u_n) {
      STAGE(cur ^ 1, u_lo + s2 + 1);                // issue next tile (async)
      asm volatile("s_waitcnt vmcnt(8)" ::: "memory");   // prev tile landed
    } else {
      asm volatile("s_waitcnt vmcnt(0)" ::: "memory");
    }
    __builtin_amdgcn_s_barrier();                   // all waves' tiles landed
    int U = (u_lo + s2) * 32;

    // S = A @ K^T (32 u cols), both row-blocks
    f32x4 s[2][2] = {{{0,0,0,0},{0,0,0,0}},{{0,0,0,0},{0,0,0,0}}};
    #pragma unroll
    for (int n2 = 0; n2 < 2; ++n2) {
      int row = n2 * 16 + (lane & 15);
      #pragma unroll
      for (int ks = 0; ks < 8; ++ks) {
        int kb = ks * 4 + (lane >> 4);
        s16x8 bfr = *(const s16x8*)(&k_lds[cur][row * 256 + ((kb ^ (row & 7)) << 3)]);
        s[0][n2] = __builtin_amdgcn_mfma_f32_16x16x32_bf16(a[0][ks], bfr, s[0][n2], 0, 0, 0);
        s[1][n2] = __builtin_amdgcn_mfma_f32_16x16x32_bf16(a[1][ks], bfr, s[1][n2], 0, 0, 0);
      }
    }
    // causal mask + bf16 + write to per-wave s_lds region (swizzled)
    #pragma unroll
    for (int rb = 0; rb < 2; ++rb) {
      #pragma unroll
      for (int n2 = 0; n2 < 2; ++n2) {
        #pragma unroll
        for (int rr = 0; rr < 4; ++rr) {
          int t_loc = wid * 32 + rb * 16 + (lane >> 4) * 4 + rr;
          int u_glob = U + n2 * 16 + (lane & 15);
          float v = (u_glob <= tt * 128 + t_loc) ? s[rb][n2][rr] : 0.0f;
          int kloc = n2 * 16 + (lane & 15);
          int cb = kloc >> 3;
          s_lds[t_loc * 32 + ((cb ^ ((t_loc >> 1) & 3)) << 3) + (kloc & 7)] = f2bf(v);
        }
      }
    }
    // PV (k=32): S from per-wave s_lds region, V from v_lds
    s16x8 af[2];
    #pragma unroll
    for (int rb = 0; rb < 2; ++rb) {
      int R = wid * 32 + rb * 16 + (lane & 15);
      int cb2 = (lane >> 4) ^ ((R >> 1) & 3);
      af[rb] = *(const s16x8*)(&s_lds[R * 32 + (cb2 << 3)]);
    }
    #pragma unroll
    for (int ni = 0; ni < 16; ++ni) {
      int vrow = ni * 16 + (lane & 15);
      int ub = (lane >> 4) ^ (vrow & 3);
      s16x8 bv = *(const s16x8*)(&v_lds[cur][vrow * 32 + (ub << 3)]);
      acc[0][ni] = __builtin_amdgcn_mfma_f32_16x16x32_bf16(af[0], bv, acc[0][ni], 0, 0, 0);
      acc[1][ni] = __builtin_amdgcn_mfma_f32_16x16x32_bf16(af[1], bv, acc[1][ni], 0, 0, 0);
    }
    asm volatile("s_waitcnt lgkmcnt(0)" ::: "memory");
    __builtin_amdgcn_s_barrier();   // all reads of buf[cur] done before reuse
  }

  // epilogue: partial sum (head + u-half) via atomics
  float* ob = out + ((size_t)b * TT + tt * 128 + wid * 32) * DD;
  #pragma unroll
  for (int rb = 0; rb < 2; ++rb) {
    #pragma unroll
    for (int ni = 0; ni < 16; ++ni) {
      int col = ni * 16 + (lane & 15);
      #pragma unroll
      for (int rr = 0; rr < 4; ++rr) {
        int row = rb * 16 + (lane >> 4) * 4 + rr;
        atomicAdd(&ob[row * DD + col], acc[rb][ni][rr]);
      }
    }
  }
#undef STAGE
}

// ---------------------------------------------------------------------------
extern "C" void kernel_launch(void* const* d_in, const int* in_sizes, int n_in,
                              void* d_out, int out_size, void* d_ws, size_t ws_size,
                              hipStream_t stream) {
  const float* r = (const float*)d_in[0];
  const float* Q = (const float*)d_in[1];
  const float* E = (const float*)d_in[2];
  float* out = (float*)d_out;
  char* ws = (char*)d_ws;

  size_t off = 0;
  short* rbf = (short*)(ws + off); off += (size_t)BB * TT * DD * 2;      // 4 MiB
  short* Qt  = (short*)(ws + off); off += (size_t)HH * DD * DD * 2;      // 1 MiB
  short* Ebf = (short*)(ws + off); off += (size_t)HH * DD * DD * 2;      // 1 MiB
  short* Abf = (short*)(ws + off); off += (size_t)BB * HH * TT * DD * 2; // 32 MiB
  short* Vtb = (short*)(ws + off); off += (size_t)BB * HH * DD * TT * 2; // 32 MiB

  hipMemsetAsync(d_out, 0, (size_t)out_size * sizeof(float), stream);
  cast_rE<<<1024, 256, 0, stream>>>(r, E, rbf, Ebf);
  qt_prep<<<dim3(16, HH), 256, 0, stream>>>(Q, Qt);
  prep_gemm<<<dim3(256, HH, BB), 256, 0, stream>>>(rbf, Qt, Ebf, Abf, Vtb);
  attn_main<<<dim3(768, 1, 1), 256, 0, stream>>>(Abf, rbf, Vtb, out);
}